// Round 1
// baseline (223.805 us; speedup 1.0000x reference)
//
#include <hip/hip_runtime.h>
#include <hip/hip_bf16.h>
#include <stdint.h>

#define TT 2048
#define CC 1024
#define NH 16
#define HD 64

typedef __attribute__((ext_vector_type(8))) short short8;
typedef __attribute__((ext_vector_type(4))) float floatx4;
typedef __attribute__((ext_vector_type(4))) unsigned short ushortx4;

typedef const __attribute__((address_space(1))) void gas_void;
typedef __attribute__((address_space(3))) void las_void;

__device__ __forceinline__ void gload16(const void* g, void* l) {
  __builtin_amdgcn_global_load_lds((gas_void*)g, (las_void*)l, 16, 0, 0);
}

__device__ __forceinline__ unsigned short f2bf(float f) {
  union { float f; uint32_t u; } v; v.f = f;
  uint32_t u = v.u;
  uint32_t r = (u + 0x7fffu + ((u >> 16) & 1u)) >> 16;
  return (unsigned short)r;
}

// ---------------- f32 -> bf16 conversion (vectorized) ----------------
__global__ __launch_bounds__(256) void cvt_bf16(const float* __restrict__ in,
                                                unsigned short* __restrict__ out,
                                                int n4) {
  const int i = blockIdx.x * blockDim.x + threadIdx.x;
  if (i >= n4) return;
  const float4 v = reinterpret_cast<const float4*>(in)[i];
  ushortx4 o;
  o[0] = f2bf(v.x); o[1] = f2bf(v.y); o[2] = f2bf(v.z); o[3] = f2bf(v.w);
  reinterpret_cast<ushortx4*>(out)[i] = o;
}

// ---------------- GEMM: C[m][n] = sum_k A[m][k]*W[n][k] + bias[n] ----------------
// A:[M][K] bf16, W:[N][K] bf16 (torch Linear weight layout). BM=BN=128, BK=64.
// 256 threads = 4 waves in 2x2; each wave computes a 64x64 sub-tile (4x4 MFMA frags).
// LDS tiles are [row][64] bf16 with 16B-chunk XOR swizzle (chunk ^= row&7), staged
// via global_load_lds with the inverse permutation applied to the GLOBAL source.
template<int OUTF32>
__global__ __launch_bounds__(256) void gemm_bt(const unsigned short* __restrict__ A,
                                               const unsigned short* __restrict__ W,
                                               const float* __restrict__ bias,
                                               void* __restrict__ outv,
                                               int M, int N, int K) {
  __shared__ unsigned short lsA[128 * 64];
  __shared__ unsigned short lsB[128 * 64];
  const int tid = threadIdx.x;
  const int wave = tid >> 6, lane = tid & 63;
  const int m0 = blockIdx.y * 128, n0 = blockIdx.x * 128;
  const int wm = (wave >> 1) * 64, wn = (wave & 1) * 64;

  floatx4 acc[4][4];
#pragma unroll
  for (int i = 0; i < 4; ++i)
#pragma unroll
    for (int j = 0; j < 4; ++j)
      acc[i][j] = (floatx4){0.f, 0.f, 0.f, 0.f};

  const int sr = lane >> 3;   // row within 8-row group
  const int sj = lane & 7;    // 16B chunk slot within row

  for (int kt = 0; kt < K; kt += 64) {
    __syncthreads();  // previous tile fully consumed
#pragma unroll
    for (int t = 0; t < 4; ++t) {
      const int g4 = wave * 4 + t;            // 0..15 (64-chunk group)
      const int r = g4 * 8 + sr;              // tile row 0..127
      const int gj = (sj ^ (r & 7)) << 3;     // swizzled source column (elements)
      gload16(A + (size_t)(m0 + r) * K + kt + gj, (char*)lsA + g4 * 1024);
      gload16(W + (size_t)(n0 + r) * K + kt + gj, (char*)lsB + g4 * 1024);
    }
    __syncthreads();  // staging visible (compiler drains vmcnt before barrier)

#pragma unroll
    for (int kk = 0; kk < 2; ++kk) {
      short8 af[4], bfr[4];
#pragma unroll
      for (int i = 0; i < 4; ++i) {
        const int ra = wm + i * 16 + (lane & 15);
        const int ca = (kk * 4 + (lane >> 4)) ^ (ra & 7);
        af[i] = *reinterpret_cast<const short8*>((const char*)lsA + ra * 128 + (ca << 4));
        const int rb = wn + i * 16 + (lane & 15);
        const int cb = (kk * 4 + (lane >> 4)) ^ (rb & 7);
        bfr[i] = *reinterpret_cast<const short8*>((const char*)lsB + rb * 128 + (cb << 4));
      }
#pragma unroll
      for (int i = 0; i < 4; ++i)
#pragma unroll
        for (int j = 0; j < 4; ++j)
          acc[i][j] = __builtin_amdgcn_mfma_f32_16x16x32_bf16(af[i], bfr[j], acc[i][j], 0, 0, 0);
    }
  }

  // epilogue: C/D layout row=(l>>4)*4+reg, col=l&15
  const int col = lane & 15;
  const int rgrp = (lane >> 4) * 4;
#pragma unroll
  for (int i = 0; i < 4; ++i) {
    const int gm0 = m0 + wm + i * 16 + rgrp;
#pragma unroll
    for (int j = 0; j < 4; ++j) {
      const int gn = n0 + wn + j * 16 + col;
      const float bv = bias[gn];
#pragma unroll
      for (int r = 0; r < 4; ++r) {
        const float v = acc[i][j][r] + bv;
        if (OUTF32)
          reinterpret_cast<float*>(outv)[(size_t)(gm0 + r) * N + gn] = v;
        else
          reinterpret_cast<unsigned short*>(outv)[(size_t)(gm0 + r) * N + gn] = f2bf(v);
      }
    }
  }
}

// ---------------- V transpose: Vt[bh][d][t] = V[b*T+t][h*64+d] ----------------
__global__ __launch_bounds__(256) void transpose_v(const unsigned short* __restrict__ Vb,
                                                   unsigned short* __restrict__ Vt) {
  __shared__ unsigned short ls[64][65];
  const int tid = threadIdx.x;
  const int bh = blockIdx.y;
  const int b = bh >> 4, h = bh & 15;
  const int t0 = blockIdx.x * 64;
#pragma unroll
  for (int i = 0; i < 16; ++i) {
    const int e = tid + i * 256;
    const int r = e >> 6, c = e & 63;
    ls[r][c] = Vb[(size_t)(b * TT + t0 + r) * CC + h * HD + c];
  }
  __syncthreads();
#pragma unroll
  for (int i = 0; i < 16; ++i) {
    const int e = tid + i * 256;
    const int d = e >> 6, t = e & 63;
    Vt[(size_t)(bh * HD + d) * TT + t0 + t] = ls[t][d];
  }
}

// ---------------- Flash attention (non-causal), bf16 MFMA ----------------
// Grid: (T/64, B*H). 4 waves; wave w owns q-rows [blk*64 + w*16, +16). KBLK=64.
__global__ __launch_bounds__(256) void attn_fwd(const unsigned short* __restrict__ Qb,
                                                const unsigned short* __restrict__ Kb,
                                                const unsigned short* __restrict__ Vt,
                                                unsigned short* __restrict__ Ob) {
  __shared__ unsigned short lsK[64 * 64];       // [kv][d], swizzled chunks
  __shared__ unsigned short lsV[64 * 64];       // [d][kv], swizzled chunks
  __shared__ unsigned short lsP[4][16 * 64];    // per-wave P tile [qrow][kv]
  const int tid = threadIdx.x;
  const int wave = tid >> 6, lane = tid & 63;
  const int bh = blockIdx.y;
  const int b = bh >> 4, h = bh & 15;
  const int q0 = blockIdx.x * 64 + wave * 16;

  // Q fragments: lane l -> q-row l%16, k = 32*kk + 8*(l/16)+i
  short8 qf[2];
  {
    const unsigned short* qp =
        Qb + (size_t)(b * TT + q0 + (lane & 15)) * CC + h * HD + ((lane >> 4) << 3);
    qf[0] = *reinterpret_cast<const short8*>(qp);
    qf[1] = *reinterpret_cast<const short8*>(qp + 32);
  }

  floatx4 o[4];
#pragma unroll
  for (int f = 0; f < 4; ++f) o[f] = (floatx4){0.f, 0.f, 0.f, 0.f};
  float mrow[4], lrow[4];
#pragma unroll
  for (int r = 0; r < 4; ++r) { mrow[r] = -3.0e38f; lrow[r] = 0.f; }

  const int sr = lane >> 3, sj = lane & 7;

  for (int kt = 0; kt < TT; kt += 64) {
    __syncthreads();
#pragma unroll
    for (int t = 0; t < 2; ++t) {
      const int g8 = wave * 2 + t;            // 0..7
      const int r = g8 * 8 + sr;              // 0..63
      const int gj = (sj ^ (r & 7)) << 3;
      gload16(Kb + (size_t)(b * TT + kt + r) * CC + h * HD + gj, (char*)lsK + g8 * 1024);
      gload16(Vt + (size_t)(bh * HD + r) * TT + kt + gj, (char*)lsV + g8 * 1024);
    }
    __syncthreads();

    // S = Q K^T
    floatx4 s[4];
#pragma unroll
    for (int cb = 0; cb < 4; ++cb) s[cb] = (floatx4){0.f, 0.f, 0.f, 0.f};
#pragma unroll
    for (int kk = 0; kk < 2; ++kk) {
#pragma unroll
      for (int cb = 0; cb < 4; ++cb) {
        const int rk = cb * 16 + (lane & 15);
        const int ck = (kk * 4 + (lane >> 4)) ^ (rk & 7);
        const short8 kf = *reinterpret_cast<const short8*>((const char*)lsK + rk * 128 + (ck << 4));
        s[cb] = __builtin_amdgcn_mfma_f32_16x16x32_bf16(qf[kk], kf, s[cb], 0, 0, 0);
      }
    }
#pragma unroll
    for (int cb = 0; cb < 4; ++cb)
#pragma unroll
      for (int r = 0; r < 4; ++r) s[cb][r] *= 0.125f;

    // online softmax: row r held by 16-lane group, reg r%4
    float tm[4];
#pragma unroll
    for (int r = 0; r < 4; ++r)
      tm[r] = fmaxf(fmaxf(s[0][r], s[1][r]), fmaxf(s[2][r], s[3][r]));
#pragma unroll
    for (int r = 0; r < 4; ++r) {
      tm[r] = fmaxf(tm[r], __shfl_xor(tm[r], 1));
      tm[r] = fmaxf(tm[r], __shfl_xor(tm[r], 2));
      tm[r] = fmaxf(tm[r], __shfl_xor(tm[r], 4));
      tm[r] = fmaxf(tm[r], __shfl_xor(tm[r], 8));
    }
    float alpha[4];
#pragma unroll
    for (int r = 0; r < 4; ++r) {
      const float mn = fmaxf(mrow[r], tm[r]);
      alpha[r] = __expf(mrow[r] - mn);
      mrow[r] = mn;
      lrow[r] *= alpha[r];
    }
#pragma unroll
    for (int f = 0; f < 4; ++f)
#pragma unroll
      for (int r = 0; r < 4; ++r) o[f][r] *= alpha[r];

    // P = exp(S - m); write to per-wave LDS tile in A-frag layout source
    float psum[4] = {0.f, 0.f, 0.f, 0.f};
#pragma unroll
    for (int cb = 0; cb < 4; ++cb) {
#pragma unroll
      for (int r = 0; r < 4; ++r) {
        const float p = __expf(s[cb][r] - mrow[r]);
        psum[r] += p;
        const int prow = (lane >> 4) * 4 + r;
        const int pcol = cb * 16 + (lane & 15);
        const int pchunk = (pcol >> 3) ^ (prow & 7);
        *reinterpret_cast<unsigned short*>((char*)lsP[wave] + prow * 128 + (pchunk << 4) +
                                           (pcol & 7) * 2) = f2bf(p);
      }
    }
#pragma unroll
    for (int r = 0; r < 4; ++r) {
      psum[r] += __shfl_xor(psum[r], 1);
      psum[r] += __shfl_xor(psum[r], 2);
      psum[r] += __shfl_xor(psum[r], 4);
      psum[r] += __shfl_xor(psum[r], 8);
      lrow[r] += psum[r];
    }
    // cross-lane LDS data dependency within the wave: drain + pin (rule 18)
    asm volatile("s_waitcnt lgkmcnt(0)" ::: "memory");
    __builtin_amdgcn_sched_barrier(0);

    // O += P V
#pragma unroll
    for (int kk = 0; kk < 2; ++kk) {
      const int pr = lane & 15;
      const int pc = (kk * 4 + (lane >> 4)) ^ (pr & 7);
      const short8 pf =
          *reinterpret_cast<const short8*>((const char*)lsP[wave] + pr * 128 + (pc << 4));
#pragma unroll
      for (int f = 0; f < 4; ++f) {
        const int rv = f * 16 + (lane & 15);
        const int cv = (kk * 4 + (lane >> 4)) ^ (rv & 7);
        const short8 vf =
            *reinterpret_cast<const short8*>((const char*)lsV + rv * 128 + (cv << 4));
        o[f] = __builtin_amdgcn_mfma_f32_16x16x32_bf16(pf, vf, o[f], 0, 0, 0);
      }
    }
  }

  // epilogue: normalize and store bf16
#pragma unroll
  for (int f = 0; f < 4; ++f) {
#pragma unroll
    for (int r = 0; r < 4; ++r) {
      const float v = o[f][r] / lrow[r];
      const int gm = b * TT + q0 + (lane >> 4) * 4 + r;
      const int gn = h * HD + f * 16 + (lane & 15);
      Ob[(size_t)gm * CC + gn] = f2bf(v);
    }
  }
}

extern "C" void kernel_launch(void* const* d_in, const int* in_sizes, int n_in,
                              void* d_out, int out_size, void* d_ws, size_t ws_size,
                              hipStream_t stream) {
  (void)in_sizes; (void)n_in; (void)out_size; (void)ws_size;
  const float* x  = (const float*)d_in[0];
  const float* Wk = (const float*)d_in[1];
  const float* bk = (const float*)d_in[2];
  const float* Wq = (const float*)d_in[3];
  const float* bq = (const float*)d_in[4];
  const float* Wv = (const float*)d_in[5];
  const float* bv = (const float*)d_in[6];
  const float* Wp = (const float*)d_in[7];
  const float* bp = (const float*)d_in[8];
  float* out = (float*)d_out;

  char* ws = (char*)d_ws;
  const size_t MB = 1u << 20;
  unsigned short* xb  = (unsigned short*)(ws);            // 8 MB  [4096][1024]
  unsigned short* Wqb = (unsigned short*)(ws + 8 * MB);   // 2 MB
  unsigned short* Wkb = (unsigned short*)(ws + 10 * MB);  // 2 MB
  unsigned short* Wvb = (unsigned short*)(ws + 12 * MB);  // 2 MB
  unsigned short* Wpb = (unsigned short*)(ws + 14 * MB);  // 2 MB
  unsigned short* Qb  = (unsigned short*)(ws + 16 * MB);  // 8 MB
  unsigned short* Kb  = (unsigned short*)(ws + 24 * MB);  // 8 MB
  unsigned short* Vb  = (unsigned short*)(ws + 32 * MB);  // 8 MB
  unsigned short* Vtb = (unsigned short*)(ws + 40 * MB);  // 8 MB [bh][64][2048]
  unsigned short* Ab  = (unsigned short*)(ws + 48 * MB);  // 8 MB

  const int M = 2 * TT;  // 4096

  cvt_bf16<<<(M * CC / 4 + 255) / 256, 256, 0, stream>>>(x, xb, M * CC / 4);
  cvt_bf16<<<(CC * CC / 4 + 255) / 256, 256, 0, stream>>>(Wq, Wqb, CC * CC / 4);
  cvt_bf16<<<(CC * CC / 4 + 255) / 256, 256, 0, stream>>>(Wk, Wkb, CC * CC / 4);
  cvt_bf16<<<(CC * CC / 4 + 255) / 256, 256, 0, stream>>>(Wv, Wvb, CC * CC / 4);
  cvt_bf16<<<(CC * CC / 4 + 255) / 256, 256, 0, stream>>>(Wp, Wpb, CC * CC / 4);

  dim3 gg(CC / 128, M / 128);  // (8, 32)
  gemm_bt<0><<<gg, 256, 0, stream>>>(xb, Wqb, bq, Qb, M, CC, CC);
  gemm_bt<0><<<gg, 256, 0, stream>>>(xb, Wkb, bk, Kb, M, CC, CC);
  gemm_bt<0><<<gg, 256, 0, stream>>>(xb, Wvb, bv, Vb, M, CC, CC);

  transpose_v<<<dim3(TT / 64, 2 * NH), 256, 0, stream>>>(Vb, Vtb);

  attn_fwd<<<dim3(TT / 64, 2 * NH), 256, 0, stream>>>(Qb, Kb, Vtb, Ab);

  gemm_bt<1><<<gg, 256, 0, stream>>>(Ab, Wpb, bp, out, M, CC, CC);
}

// Round 2
// 158.092 us; speedup vs baseline: 1.4157x; 1.4157x over previous
//
#include <hip/hip_runtime.h>
#include <hip/hip_bf16.h>
#include <stdint.h>

#define TT 2048
#define CC 1024
#define NH 16
#define HD 64
#define QKVN 3072

typedef __attribute__((ext_vector_type(8))) short short8;
typedef __attribute__((ext_vector_type(4))) short short4v;
typedef __attribute__((ext_vector_type(4))) float floatx4;
typedef __attribute__((ext_vector_type(4))) unsigned short ushortx4;

typedef const __attribute__((address_space(1))) void gas_void;
typedef __attribute__((address_space(3))) void las_void;

__device__ __forceinline__ void gload16(const void* g, void* l) {
  __builtin_amdgcn_global_load_lds((gas_void*)g, (las_void*)l, 16, 0, 0);
}

__device__ __forceinline__ unsigned short f2bf(float f) {
  union { float f; uint32_t u; } v; v.f = f;
  uint32_t u = v.u;
  uint32_t r = (u + 0x7fffu + ((u >> 16) & 1u)) >> 16;
  return (unsigned short)r;
}

__device__ __forceinline__ float fexp2(float x) {
#if __has_builtin(__builtin_amdgcn_exp2f)
  return __builtin_amdgcn_exp2f(x);
#else
  return exp2f(x);
#endif
}

// ---------------- f32 -> bf16 conversion (vectorized) ----------------
__global__ __launch_bounds__(256) void cvt_bf16(const float* __restrict__ in,
                                                unsigned short* __restrict__ out,
                                                int n4) {
  const int i = blockIdx.x * blockDim.x + threadIdx.x;
  if (i >= n4) return;
  const float4 v = reinterpret_cast<const float4*>(in)[i];
  ushortx4 o;
  o[0] = f2bf(v.x); o[1] = f2bf(v.y); o[2] = f2bf(v.z); o[3] = f2bf(v.w);
  reinterpret_cast<ushortx4*>(out)[i] = o;
}

// ---------------- GEMM: C[m][n] = sum_k A[m][k]*W[n][k] + bias[n] ----------------
// 128x128x64 tile, 4 waves 2x2 (64x64 each). Bias segment selected by n0>>10
// (128-tiles never straddle a 1024 boundary).
template<int OUTF32>
__global__ __launch_bounds__(256) void gemm_bt(const unsigned short* __restrict__ A,
                                               const unsigned short* __restrict__ W,
                                               const float* __restrict__ b0,
                                               const float* __restrict__ b1,
                                               const float* __restrict__ b2,
                                               void* __restrict__ outv,
                                               int M, int N, int K) {
  __shared__ unsigned short lsA[128 * 64];
  __shared__ unsigned short lsB[128 * 64];
  const int tid = threadIdx.x;
  const int wave = tid >> 6, lane = tid & 63;
  const int m0 = blockIdx.y * 128, n0 = blockIdx.x * 128;
  const int wm = (wave >> 1) * 64, wn = (wave & 1) * 64;
  const float* bias = (n0 < 1024) ? b0 : (n0 < 2048 ? b1 : b2);

  floatx4 acc[4][4];
#pragma unroll
  for (int i = 0; i < 4; ++i)
#pragma unroll
    for (int j = 0; j < 4; ++j)
      acc[i][j] = (floatx4){0.f, 0.f, 0.f, 0.f};

  const int sr = lane >> 3;
  const int sj = lane & 7;

  for (int kt = 0; kt < K; kt += 64) {
    __syncthreads();
#pragma unroll
    for (int t = 0; t < 4; ++t) {
      const int g4 = wave * 4 + t;
      const int r = g4 * 8 + sr;
      const int gj = (sj ^ (r & 7)) << 3;
      gload16(A + (size_t)(m0 + r) * K + kt + gj, (char*)lsA + g4 * 1024);
      gload16(W + (size_t)(n0 + r) * K + kt + gj, (char*)lsB + g4 * 1024);
    }
    __syncthreads();

#pragma unroll
    for (int kk = 0; kk < 2; ++kk) {
      short8 af[4], bfr[4];
#pragma unroll
      for (int i = 0; i < 4; ++i) {
        const int ra = wm + i * 16 + (lane & 15);
        const int ca = (kk * 4 + (lane >> 4)) ^ (ra & 7);
        af[i] = *reinterpret_cast<const short8*>((const char*)lsA + ra * 128 + (ca << 4));
        const int rb = wn + i * 16 + (lane & 15);
        const int cb = (kk * 4 + (lane >> 4)) ^ (rb & 7);
        bfr[i] = *reinterpret_cast<const short8*>((const char*)lsB + rb * 128 + (cb << 4));
      }
#pragma unroll
      for (int i = 0; i < 4; ++i)
#pragma unroll
        for (int j = 0; j < 4; ++j)
          acc[i][j] = __builtin_amdgcn_mfma_f32_16x16x32_bf16(af[i], bfr[j], acc[i][j], 0, 0, 0);
    }
  }

  const int col = lane & 15;
  const int rgrp = (lane >> 4) * 4;
#pragma unroll
  for (int i = 0; i < 4; ++i) {
    const int gm0 = m0 + wm + i * 16 + rgrp;
#pragma unroll
    for (int j = 0; j < 4; ++j) {
      const int gn = n0 + wn + j * 16 + col;
      const float bv = bias[gn & 1023];
#pragma unroll
      for (int r = 0; r < 4; ++r) {
        const float v = acc[i][j][r] + bv;
        if (OUTF32)
          reinterpret_cast<float*>(outv)[(size_t)(gm0 + r) * N + gn] = v;
        else
          reinterpret_cast<unsigned short*>(outv)[(size_t)(gm0 + r) * N + gn] = f2bf(v);
      }
    }
  }
}

// ---------------- V transpose: Vt[bh][d][t] = QKV[b*T+t][2048 + h*64 + d] ----------------
__global__ __launch_bounds__(256) void transpose_v(const unsigned short* __restrict__ QKV,
                                                   unsigned short* __restrict__ Vt) {
  __shared__ unsigned short ls[64][65];
  const int tid = threadIdx.x;
  const int bh = blockIdx.y;
  const int b = bh >> 4, h = bh & 15;
  const int t0 = blockIdx.x * 64;
#pragma unroll
  for (int i = 0; i < 16; ++i) {
    const int e = tid + i * 256;
    const int r = e >> 6, c = e & 63;
    ls[r][c] = QKV[(size_t)(b * TT + t0 + r) * QKVN + 2 * CC + h * HD + c];
  }
  __syncthreads();
#pragma unroll
  for (int i = 0; i < 16; ++i) {
    const int e = tid + i * 256;
    const int d = e >> 6, t = e & 63;
    Vt[(size_t)(bh * HD + d) * TT + t0 + t] = ls[t][d];
  }
}

// ---------------- Flash attention, swapped QK^T, in-register softmax ----------------
// Grid: (T/64, B*H). 4 waves; wave w owns q-rows [blk*64 + w*16, +16). KBLK=64.
// S^T = mfma(A=K, B=Q): col=q=lane&15, row=kv. P redistributed to B-frag via
// cvt_pk_bf16 + permlane32_swap (no LDS round trip). PV: O^T += V^T * P^T.
__global__ __launch_bounds__(256) void attn_fwd(const unsigned short* __restrict__ QKV,
                                                const unsigned short* __restrict__ Vt,
                                                unsigned short* __restrict__ Ob) {
  __shared__ unsigned short lsK[2][64 * 64];
  __shared__ unsigned short lsV[2][64 * 64];
  const int tid = threadIdx.x;
  const int wave = tid >> 6, lane = tid & 63;
  const int g = lane >> 4;      // 16-lane group
  const int c16 = lane & 15;    // q column
  const int bh = blockIdx.y;
  const int b = bh >> 4, h = bh & 15;
  const int q0 = blockIdx.x * 64 + wave * 16;

  // Q as B-operand fragment: col=q=lane&15, k=(lane>>4)*8+i (+32 per kk)
  short8 qf[2];
  {
    const unsigned short* qp =
        QKV + (size_t)(b * TT + q0 + c16) * QKVN + h * HD + g * 8;
    qf[0] = *reinterpret_cast<const short8*>(qp);
    qf[1] = *reinterpret_cast<const short8*>(qp + 32);
  }

  floatx4 o[4];
#pragma unroll
  for (int f = 0; f < 4; ++f) o[f] = (floatx4){0.f, 0.f, 0.f, 0.f};
  float m = -3.0e38f, l = 0.f;

  const int sr = lane >> 3, sj = lane & 7;

  auto stage = [&](int buf, int kt) {
#pragma unroll
    for (int t = 0; t < 2; ++t) {
      const int g8 = wave * 2 + t;
      const int r = g8 * 8 + sr;
      const int gj = (sj ^ (r & 7)) << 3;
      gload16(QKV + (size_t)(b * TT + kt + r) * QKVN + CC + h * HD + gj,
              (char*)lsK[buf] + g8 * 1024);
      gload16(Vt + ((size_t)bh * HD + r) * TT + kt + gj, (char*)lsV[buf] + g8 * 1024);
    }
  };

  stage(0, 0);
  __syncthreads();

  int cur = 0;
  for (int kt = 0; kt < TT; kt += 64, cur ^= 1) {
    if (kt + 64 < TT) stage(cur ^ 1, kt + 64);   // prefetch next tile (overlaps compute)

    // S^T = K * Q^T : s[cb][r] = S[kv = cb*16 + g*4 + r][q = c16] (pre-scale)
    floatx4 s[4];
#pragma unroll
    for (int cb = 0; cb < 4; ++cb) s[cb] = (floatx4){0.f, 0.f, 0.f, 0.f};
#pragma unroll
    for (int kk = 0; kk < 2; ++kk) {
#pragma unroll
      for (int cb = 0; cb < 4; ++cb) {
        const int rk = cb * 16 + c16;
        const int ck = (kk * 4 + g) ^ (rk & 7);
        const short8 kf =
            *reinterpret_cast<const short8*>((const char*)lsK[cur] + rk * 128 + (ck << 4));
        s[cb] = __builtin_amdgcn_mfma_f32_16x16x32_bf16(kf, qf[kk], s[cb], 0, 0, 0);
      }
    }
    // to log2 domain: s *= (1/8)*log2(e)
    const float SC = 0.18033688011112042f;
#pragma unroll
    for (int cb = 0; cb < 4; ++cb)
#pragma unroll
      for (int r = 0; r < 4; ++r) s[cb][r] *= SC;

    // column (per-q) max over this tile's 64 kv: 16 local + 2 shfl
    float tm = s[0][0];
#pragma unroll
    for (int cb = 0; cb < 4; ++cb)
#pragma unroll
      for (int r = 0; r < 4; ++r) tm = fmaxf(tm, s[cb][r]);
    tm = fmaxf(tm, __shfl_xor(tm, 16));
    tm = fmaxf(tm, __shfl_xor(tm, 32));

    // deferred-max rescale (THR=8 in log2 domain -> P bounded by 256)
    if (__any(tm > m + 8.0f)) {
      const float mn = fmaxf(m, tm);
      const float al = fexp2(m - mn);
      m = mn;
      l *= al;
#pragma unroll
      for (int f = 0; f < 4; ++f)
#pragma unroll
        for (int r = 0; r < 4; ++r) o[f][r] *= al;
    }

    // P = 2^(s - m), column sum
    float ps = 0.f;
#pragma unroll
    for (int cb = 0; cb < 4; ++cb)
#pragma unroll
      for (int r = 0; r < 4; ++r) {
        const float p = fexp2(s[cb][r] - m);
        s[cb][r] = p;
        ps += p;
      }
    ps += __shfl_xor(ps, 16);
    ps += __shfl_xor(ps, 32);
    l += ps;

    // pack P to bf16 pairs: w[cb][h] = pk(p[2h], p[2h+1])
    unsigned int w[4][2];
#pragma unroll
    for (int cb = 0; cb < 4; ++cb) {
      asm("v_cvt_pk_bf16_f32 %0, %1, %2" : "=v"(w[cb][0]) : "v"(s[cb][0]), "v"(s[cb][1]));
      asm("v_cvt_pk_bf16_f32 %0, %1, %2" : "=v"(w[cb][1]) : "v"(s[cb][2]), "v"(s[cb][3]));
    }

    // O^T += V^T * P^T.  B-frag k-index kappa <-> C-row swap-bits-2,3; realized by
    // permlane32_swap on the packed pairs + matching V read pattern.
#pragma unroll
    for (int kk = 0; kk < 2; ++kk) {
      unsigned int pa0 = w[2 * kk][0], pb0 = w[2 * kk + 1][0];
      unsigned int pa1 = w[2 * kk][1], pb1 = w[2 * kk + 1][1];
      asm volatile("v_permlane32_swap_b32 %0, %1" : "+v"(pa0), "+v"(pb0));
      asm volatile("v_permlane32_swap_b32 %0, %1" : "+v"(pa1), "+v"(pb1));
      union { unsigned int u[4]; short8 v; } pb;
      pb.u[0] = pa0; pb.u[1] = pa1; pb.u[2] = pb0; pb.u[3] = pb1;

      const int cbase = 4 * kk + 2 * (g >> 1);   // 16B chunk of first kv run
      const int boff = (g & 1) * 8;              // byte offset within chunk
#pragma unroll
      for (int f = 0; f < 4; ++f) {
        const int rv = f * 16 + c16;             // d row
        const int chA = cbase ^ (rv & 7);
        const int chB = (cbase + 1) ^ (rv & 7);
        union { short4v h[2]; short8 v; } vf;
        vf.h[0] = *reinterpret_cast<const short4v*>((const char*)lsV[cur] + rv * 128 +
                                                    (chA << 4) + boff);
        vf.h[1] = *reinterpret_cast<const short4v*>((const char*)lsV[cur] + rv * 128 +
                                                    (chB << 4) + boff);
        o[f] = __builtin_amdgcn_mfma_f32_16x16x32_bf16(vf.v, pb.v, o[f], 0, 0, 0);
      }
    }
    __syncthreads();   // staged tile ready (vmcnt drained) + buffer consumed by all
  }

  // epilogue: O[q][d] = O^T/l, vectorized 8B stores
  const float inv = 1.0f / l;
  const size_t gm = (size_t)(b * TT + q0 + c16) * CC;
#pragma unroll
  for (int f = 0; f < 4; ++f) {
    ushortx4 ov;
#pragma unroll
    for (int r = 0; r < 4; ++r) ov[r] = f2bf(o[f][r] * inv);
    *reinterpret_cast<ushortx4*>(&Ob[gm + h * HD + f * 16 + 4 * g]) = ov;
  }
}

extern "C" void kernel_launch(void* const* d_in, const int* in_sizes, int n_in,
                              void* d_out, int out_size, void* d_ws, size_t ws_size,
                              hipStream_t stream) {
  (void)in_sizes; (void)n_in; (void)out_size; (void)ws_size;
  const float* x  = (const float*)d_in[0];
  const float* Wk = (const float*)d_in[1];
  const float* bk = (const float*)d_in[2];
  const float* Wq = (const float*)d_in[3];
  const float* bq = (const float*)d_in[4];
  const float* Wv = (const float*)d_in[5];
  const float* bv = (const float*)d_in[6];
  const float* Wp = (const float*)d_in[7];
  const float* bp = (const float*)d_in[8];
  float* out = (float*)d_out;

  char* ws = (char*)d_ws;
  const size_t MB = 1u << 20;
  unsigned short* xb    = (unsigned short*)(ws);            // 8 MB  [4096][1024]
  unsigned short* Wqkvb = (unsigned short*)(ws + 8 * MB);   // 6 MB  [3072][1024] (q,k,v)
  unsigned short* Wpb   = (unsigned short*)(ws + 14 * MB);  // 2 MB
  unsigned short* QKVb  = (unsigned short*)(ws + 16 * MB);  // 24 MB [4096][3072]
  unsigned short* Vtb   = (unsigned short*)(ws + 40 * MB);  // 8 MB  [32][64][2048]
  unsigned short* Ab    = (unsigned short*)(ws + 48 * MB);  // 8 MB  [4096][1024]

  const int M = 2 * TT;  // 4096

  cvt_bf16<<<(M * CC / 4 + 255) / 256, 256, 0, stream>>>(x, xb, M * CC / 4);
  cvt_bf16<<<(CC * CC / 4 + 255) / 256, 256, 0, stream>>>(Wq, Wqkvb, CC * CC / 4);
  cvt_bf16<<<(CC * CC / 4 + 255) / 256, 256, 0, stream>>>(Wk, Wqkvb + CC * CC, CC * CC / 4);
  cvt_bf16<<<(CC * CC / 4 + 255) / 256, 256, 0, stream>>>(Wv, Wqkvb + 2 * CC * CC, CC * CC / 4);
  cvt_bf16<<<(CC * CC / 4 + 255) / 256, 256, 0, stream>>>(Wp, Wpb, CC * CC / 4);

  // fused QKV GEMM: [4096][1024] x [3072][1024]^T -> [4096][3072]
  gemm_bt<0><<<dim3(QKVN / 128, M / 128), 256, 0, stream>>>(xb, Wqkvb, bq, bk, bv, QKVb,
                                                            M, QKVN, CC);

  transpose_v<<<dim3(TT / 64, 2 * NH), 256, 0, stream>>>(QKVb, Vtb);

  attn_fwd<<<dim3(TT / 64, 2 * NH), 256, 0, stream>>>(QKVb, Vtb, Ab);

  gemm_bt<1><<<dim3(CC / 128, M / 128), 256, 0, stream>>>(Ab, Wpb, bp, bp, bp, out,
                                                          M, CC, CC);
}

// Round 3
// 136.959 us; speedup vs baseline: 1.6341x; 1.1543x over previous
//
#include <hip/hip_runtime.h>
#include <hip/hip_bf16.h>
#include <stdint.h>

#define TT 2048
#define CC 1024
#define NH 16
#define HD 64
#define QKVN 3072

typedef __attribute__((ext_vector_type(8))) short short8;
typedef __attribute__((ext_vector_type(4))) float floatx4;
typedef __attribute__((ext_vector_type(4))) unsigned short ushortx4;

typedef const __attribute__((address_space(1))) void gas_void;
typedef __attribute__((address_space(3))) void las_void;

__device__ __forceinline__ void gload16(const void* g, void* l) {
  __builtin_amdgcn_global_load_lds((gas_void*)g, (las_void*)l, 16, 0, 0);
}

__device__ __forceinline__ unsigned short f2bf(float f) {
  union { float f; uint32_t u; } v; v.f = f;
  uint32_t u = v.u;
  uint32_t r = (u + 0x7fffu + ((u >> 16) & 1u)) >> 16;
  return (unsigned short)r;
}

__device__ __forceinline__ float fexp2(float x) {
#if __has_builtin(__builtin_amdgcn_exp2f)
  return __builtin_amdgcn_exp2f(x);
#else
  return exp2f(x);
#endif
}

// ---------------- fused f32 -> bf16 conversion for all 5 tensors ----------------
__global__ __launch_bounds__(256) void cvt_fused(const float* __restrict__ x,
                                                 const float* __restrict__ wq,
                                                 const float* __restrict__ wk,
                                                 const float* __restrict__ wv,
                                                 const float* __restrict__ wp,
                                                 unsigned short* __restrict__ xb,
                                                 unsigned short* __restrict__ wqkvb,
                                                 unsigned short* __restrict__ wpb) {
  const int i = blockIdx.x * blockDim.x + threadIdx.x;  // f4 index, total 2097152
  const float* src;
  unsigned short* dst;
  int si;
  if (i < 1048576) {            // x: 4096x1024
    src = x; dst = xb; si = i;
    const float4 v = reinterpret_cast<const float4*>(src)[si];
    ushortx4 o; o[0] = f2bf(v.x); o[1] = f2bf(v.y); o[2] = f2bf(v.z); o[3] = f2bf(v.w);
    reinterpret_cast<ushortx4*>(dst)[i] = o;
    return;
  }
  const int j = i - 1048576;     // 0..1048575 over 4 weight matrices
  const int seg = j >> 18;       // 262144 f4 per weight
  const int idx = j & 262143;
  src = (seg == 0) ? wq : (seg == 1) ? wk : (seg == 2) ? wv : wp;
  const float4 v = reinterpret_cast<const float4*>(src)[idx];
  ushortx4 o; o[0] = f2bf(v.x); o[1] = f2bf(v.y); o[2] = f2bf(v.z); o[3] = f2bf(v.w);
  if (seg < 3)
    reinterpret_cast<ushortx4*>(wqkvb)[j] = o;       // q,k,v contiguous thirds
  else
    reinterpret_cast<ushortx4*>(wpb)[idx] = o;
}

// ---------------- GEMM: C[m][n] = sum_k A[m][k]*W[n][k] + bias[n] ----------------
template<int OUTF32>
__global__ __launch_bounds__(256) void gemm_bt(const unsigned short* __restrict__ A,
                                               const unsigned short* __restrict__ W,
                                               const float* __restrict__ b0,
                                               const float* __restrict__ b1,
                                               const float* __restrict__ b2,
                                               void* __restrict__ outv,
                                               int M, int N, int K) {
  __shared__ unsigned short lsA[128 * 64];
  __shared__ unsigned short lsB[128 * 64];
  const int tid = threadIdx.x;
  const int wave = tid >> 6, lane = tid & 63;
  const int m0 = blockIdx.y * 128, n0 = blockIdx.x * 128;
  const int wm = (wave >> 1) * 64, wn = (wave & 1) * 64;
  const float* bias = (n0 < 1024) ? b0 : (n0 < 2048 ? b1 : b2);

  floatx4 acc[4][4];
#pragma unroll
  for (int i = 0; i < 4; ++i)
#pragma unroll
    for (int j = 0; j < 4; ++j)
      acc[i][j] = (floatx4){0.f, 0.f, 0.f, 0.f};

  const int sr = lane >> 3;
  const int sj = lane & 7;

  for (int kt = 0; kt < K; kt += 64) {
    __syncthreads();
#pragma unroll
    for (int t = 0; t < 4; ++t) {
      const int g4 = wave * 4 + t;
      const int r = g4 * 8 + sr;
      const int gj = (sj ^ (r & 7)) << 3;
      gload16(A + (size_t)(m0 + r) * K + kt + gj, (char*)lsA + g4 * 1024);
      gload16(W + (size_t)(n0 + r) * K + kt + gj, (char*)lsB + g4 * 1024);
    }
    __syncthreads();

#pragma unroll
    for (int kk = 0; kk < 2; ++kk) {
      short8 af[4], bfr[4];
#pragma unroll
      for (int i = 0; i < 4; ++i) {
        const int ra = wm + i * 16 + (lane & 15);
        const int ca = (kk * 4 + (lane >> 4)) ^ (ra & 7);
        af[i] = *reinterpret_cast<const short8*>((const char*)lsA + ra * 128 + (ca << 4));
        const int rb = wn + i * 16 + (lane & 15);
        const int cb = (kk * 4 + (lane >> 4)) ^ (rb & 7);
        bfr[i] = *reinterpret_cast<const short8*>((const char*)lsB + rb * 128 + (cb << 4));
      }
#pragma unroll
      for (int i = 0; i < 4; ++i)
#pragma unroll
        for (int j = 0; j < 4; ++j)
          acc[i][j] = __builtin_amdgcn_mfma_f32_16x16x32_bf16(af[i], bfr[j], acc[i][j], 0, 0, 0);
    }
  }

  const int col = lane & 15;
  const int rgrp = (lane >> 4) * 4;
#pragma unroll
  for (int i = 0; i < 4; ++i) {
    const int gm0 = m0 + wm + i * 16 + rgrp;
#pragma unroll
    for (int j = 0; j < 4; ++j) {
      const int gn = n0 + wn + j * 16 + col;
      const float bv = bias[gn & 1023];
#pragma unroll
      for (int r = 0; r < 4; ++r) {
        const float v = acc[i][j][r] + bv;
        if (OUTF32)
          reinterpret_cast<float*>(outv)[(size_t)(gm0 + r) * N + gn] = v;
        else
          reinterpret_cast<unsigned short*>(outv)[(size_t)(gm0 + r) * N + gn] = f2bf(v);
      }
    }
  }
}

// kv permutation within a 64-block: chunk c'=4kk+g holds runs [kA..kA+3, kA+8..kA+11],
// kA = 32kk + 16(g>>1) + 4(g&1)  -> PV A-fragment is a single b128 per lane.
__device__ __forceinline__ int perm64(int t) {
  const int kk = t >> 5, r5 = t & 31;
  const int g = ((r5 >> 3) & 2) | ((r5 >> 2) & 1);
  const int slot = (r5 & 3) | ((r5 >> 1) & 4);
  return kk * 32 + g * 8 + slot;
}

// ---------------- V transpose (pair-permuted): Vt[bh][d][perm(t)] ----------------
__global__ __launch_bounds__(256) void transpose_v(const unsigned short* __restrict__ QKV,
                                                   unsigned short* __restrict__ Vt) {
  __shared__ unsigned short ls[64][65];
  const int tid = threadIdx.x;
  const int bh = blockIdx.y;
  const int b = bh >> 4, h = bh & 15;
  const int t0 = blockIdx.x * 64;
#pragma unroll
  for (int i = 0; i < 16; ++i) {
    const int e = tid + i * 256;
    const int r = e >> 6, c = e & 63;
    ls[r][c] = QKV[(size_t)(b * TT + t0 + r) * QKVN + 2 * CC + h * HD + c];
  }
  __syncthreads();
#pragma unroll
  for (int i = 0; i < 16; ++i) {
    const int e = tid + i * 256;
    const int d = e >> 6, t = e & 63;
    Vt[(size_t)(bh * HD + d) * TT + t0 + perm64(t)] = ls[t][d];
  }
}

// ---------------- Flash attention: swapped QK^T, in-register softmax ----------------
// Grid (T/128, B*H); 4 waves; wave w owns q rows [blk*128 + w*32, +32) as 2 q-blocks.
__global__ __launch_bounds__(256) void attn_fwd(const unsigned short* __restrict__ QKV,
                                                const unsigned short* __restrict__ Vt,
                                                unsigned short* __restrict__ Ob) {
  __shared__ unsigned short lsK[2][64 * 64];
  __shared__ unsigned short lsV[2][64 * 64];
  const int tid = threadIdx.x;
  const int wave = tid >> 6, lane = tid & 63;
  const int g = lane >> 4;
  const int c16 = lane & 15;
  const int bh = blockIdx.y;
  const int b = bh >> 4, h = bh & 15;
  const int qw = blockIdx.x * 128 + wave * 32;

  // Q B-fragments for both q-blocks
  short8 qf[2][2];
#pragma unroll
  for (int qb = 0; qb < 2; ++qb) {
    const unsigned short* qp =
        QKV + (size_t)(b * TT + qw + qb * 16 + c16) * QKVN + h * HD + g * 8;
    qf[qb][0] = *reinterpret_cast<const short8*>(qp);
    qf[qb][1] = *reinterpret_cast<const short8*>(qp + 32);
  }

  floatx4 o[2][4];
#pragma unroll
  for (int qb = 0; qb < 2; ++qb)
#pragma unroll
    for (int f = 0; f < 4; ++f) o[qb][f] = (floatx4){0.f, 0.f, 0.f, 0.f};
  float m[2] = {-3.0e38f, -3.0e38f}, l[2] = {0.f, 0.f};

  const int sr = lane >> 3, sj = lane & 7;

  auto stage = [&](int buf, int kt) {
#pragma unroll
    for (int t = 0; t < 2; ++t) {
      const int g8 = wave * 2 + t;
      const int r = g8 * 8 + sr;
      const int gj = (sj ^ (r & 7)) << 3;
      gload16(QKV + (size_t)(b * TT + kt + r) * QKVN + CC + h * HD + gj,
              (char*)lsK[buf] + g8 * 1024);
      gload16(Vt + ((size_t)bh * HD + r) * TT + kt + gj, (char*)lsV[buf] + g8 * 1024);
    }
  };

  const float SC = 0.18033688011112042f;  // (1/8)*log2(e)

  auto compute = [&](const unsigned short* lk, const unsigned short* lv) {
    // S^T = K * Q^T
    floatx4 s[2][4];
#pragma unroll
    for (int qb = 0; qb < 2; ++qb)
#pragma unroll
      for (int cb = 0; cb < 4; ++cb) s[qb][cb] = (floatx4){0.f, 0.f, 0.f, 0.f};
    __builtin_amdgcn_s_setprio(1);
#pragma unroll
    for (int kk = 0; kk < 2; ++kk) {
#pragma unroll
      for (int cb = 0; cb < 4; ++cb) {
        const int rk = cb * 16 + c16;
        const int ck = (kk * 4 + g) ^ (rk & 7);
        const short8 kf =
            *reinterpret_cast<const short8*>((const char*)lk + rk * 128 + (ck << 4));
        s[0][cb] = __builtin_amdgcn_mfma_f32_16x16x32_bf16(kf, qf[0][kk], s[0][cb], 0, 0, 0);
        s[1][cb] = __builtin_amdgcn_mfma_f32_16x16x32_bf16(kf, qf[1][kk], s[1][cb], 0, 0, 0);
      }
    }
    __builtin_amdgcn_s_setprio(0);

    unsigned int w[2][4][2];
#pragma unroll
    for (int qb = 0; qb < 2; ++qb) {
      // tile max (raw), scaled once
      float tm = s[qb][0][0];
#pragma unroll
      for (int cb = 0; cb < 4; ++cb)
#pragma unroll
        for (int r = 0; r < 4; ++r) tm = fmaxf(tm, s[qb][cb][r]);
      tm = fmaxf(tm, __shfl_xor(tm, 16));
      tm = fmaxf(tm, __shfl_xor(tm, 32));
      tm *= SC;

      if (__any(tm > m[qb] + 8.0f)) {   // deferred-max rescale
        const float mn = fmaxf(m[qb], tm);
        const float al = fexp2(m[qb] - mn);
        m[qb] = mn;
        l[qb] *= al;
#pragma unroll
        for (int f = 0; f < 4; ++f)
#pragma unroll
          for (int r = 0; r < 4; ++r) o[qb][f][r] *= al;
      }

      float ps = 0.f;
      const float nm = -m[qb];
#pragma unroll
      for (int cb = 0; cb < 4; ++cb)
#pragma unroll
        for (int r = 0; r < 4; ++r) {
          const float p = fexp2(__builtin_fmaf(s[qb][cb][r], SC, nm));
          s[qb][cb][r] = p;
          ps += p;
        }
      ps += __shfl_xor(ps, 16);
      ps += __shfl_xor(ps, 32);
      l[qb] += ps;

#pragma unroll
      for (int cb = 0; cb < 4; ++cb) {
        asm("v_cvt_pk_bf16_f32 %0, %1, %2"
            : "=v"(w[qb][cb][0]) : "v"(s[qb][cb][0]), "v"(s[qb][cb][1]));
        asm("v_cvt_pk_bf16_f32 %0, %1, %2"
            : "=v"(w[qb][cb][1]) : "v"(s[qb][cb][2]), "v"(s[qb][cb][3]));
      }
    }

    // O^T += V^T * P^T
#pragma unroll
    for (int kk = 0; kk < 2; ++kk) {
      short8 pbv[2];
#pragma unroll
      for (int qb = 0; qb < 2; ++qb) {
        unsigned int pa0 = w[qb][2 * kk][0], pb0 = w[qb][2 * kk + 1][0];
        unsigned int pa1 = w[qb][2 * kk][1], pb1 = w[qb][2 * kk + 1][1];
        asm("v_permlane32_swap_b32 %0, %1" : "+v"(pa0), "+v"(pb0));
        asm("v_permlane32_swap_b32 %0, %1" : "+v"(pa1), "+v"(pb1));
        union { unsigned int u[4]; short8 v; } pk;
        pk.u[0] = pa0; pk.u[1] = pa1; pk.u[2] = pb0; pk.u[3] = pb1;
        pbv[qb] = pk.v;
      }
      __builtin_amdgcn_s_setprio(1);
#pragma unroll
      for (int f = 0; f < 4; ++f) {
        const int rv = f * 16 + c16;
        const int cv = (4 * kk + g) ^ (rv & 7);
        const short8 vf =
            *reinterpret_cast<const short8*>((const char*)lv + rv * 128 + (cv << 4));
        o[0][f] = __builtin_amdgcn_mfma_f32_16x16x32_bf16(vf, pbv[0], o[0][f], 0, 0, 0);
        o[1][f] = __builtin_amdgcn_mfma_f32_16x16x32_bf16(vf, pbv[1], o[1][f], 0, 0, 0);
      }
      __builtin_amdgcn_s_setprio(0);
    }
  };

  stage(0, 0);
  __syncthreads();

  for (int kt = 0; kt < TT; kt += 128) {
    stage(1, kt + 64);
    compute(lsK[0], lsV[0]);
    __syncthreads();
    if (kt + 128 < TT) stage(0, kt + 128);
    compute(lsK[1], lsV[1]);
    __syncthreads();
  }

  // epilogue
#pragma unroll
  for (int qb = 0; qb < 2; ++qb) {
    const float inv = 1.0f / l[qb];
    const size_t gm = (size_t)(b * TT + qw + qb * 16 + c16) * CC;
#pragma unroll
    for (int f = 0; f < 4; ++f) {
      ushortx4 ov;
#pragma unroll
      for (int r = 0; r < 4; ++r) ov[r] = f2bf(o[qb][f][r] * inv);
      *reinterpret_cast<ushortx4*>(&Ob[gm + h * HD + f * 16 + 4 * g]) = ov;
    }
  }
}

extern "C" void kernel_launch(void* const* d_in, const int* in_sizes, int n_in,
                              void* d_out, int out_size, void* d_ws, size_t ws_size,
                              hipStream_t stream) {
  (void)in_sizes; (void)n_in; (void)out_size; (void)ws_size;
  const float* x  = (const float*)d_in[0];
  const float* Wk = (const float*)d_in[1];
  const float* bk = (const float*)d_in[2];
  const float* Wq = (const float*)d_in[3];
  const float* bq = (const float*)d_in[4];
  const float* Wv = (const float*)d_in[5];
  const float* bv = (const float*)d_in[6];
  const float* Wp = (const float*)d_in[7];
  const float* bp = (const float*)d_in[8];
  float* out = (float*)d_out;

  char* ws = (char*)d_ws;
  const size_t MB = 1u << 20;
  unsigned short* xb    = (unsigned short*)(ws);            // 8 MB  [4096][1024]
  unsigned short* Wqkvb = (unsigned short*)(ws + 8 * MB);   // 6 MB  [3072][1024] (q,k,v)
  unsigned short* Wpb   = (unsigned short*)(ws + 14 * MB);  // 2 MB
  unsigned short* QKVb  = (unsigned short*)(ws + 16 * MB);  // 24 MB [4096][3072]
  unsigned short* Vtb   = (unsigned short*)(ws + 40 * MB);  // 8 MB  [32][64][2048] permuted
  unsigned short* Ab    = (unsigned short*)(ws + 48 * MB);  // 8 MB  [4096][1024]

  const int M = 2 * TT;  // 4096

  cvt_fused<<<8192, 256, 0, stream>>>(x, Wq, Wk, Wv, Wp, xb, Wqkvb, Wpb);

  gemm_bt<0><<<dim3(QKVN / 128, M / 128), 256, 0, stream>>>(xb, Wqkvb, bq, bk, bv, QKVb,
                                                            M, QKVN, CC);

  transpose_v<<<dim3(TT / 64, 2 * NH), 256, 0, stream>>>(QKVb, Vtb);

  attn_fwd<<<dim3(TT / 128, 2 * NH), 256, 0, stream>>>(QKVb, Vtb, Ab);

  gemm_bt<1><<<dim3(CC / 128, M / 128), 256, 0, stream>>>(Ab, Wpb, bp, bp, bp, out,
                                                          M, CC, CC);
}